// Round 2
// baseline (8039.634 us; speedup 1.0000x reference)
//
#include <hip/hip_runtime.h>

// CT-LSTM (neural Hawkes) on MI355X — robust multi-launch design.
// B=32, T=512, H=1024. Sequential dependence handled by per-step kernel
// launches (graph-friendly, deadlock-free). No d_ws, no coop launch,
// no dynamic LDS. All scratch in static __device__ arrays, rewritten
// fully on every call.

#define H   1024
#define B   32
#define T   512
#define NG  7
#define C7  7168
#define K2  2048
#define NWG 256

typedef __attribute__((ext_vector_type(4))) float f32x4;

// ---------------- static device scratch (~65 MB) ----------------
__device__ __attribute__((aligned(16))) float g_Wt[(size_t)C7 * K2]; // rec_W^T [col][k]
__device__ __attribute__((aligned(16))) float g_w1t[(size_t)H * H];  // w1^T [j][k]
__device__ __attribute__((aligned(16))) float g_w2t[(size_t)H * H];  // w2^T [j][k]
__device__ __attribute__((aligned(16))) float g_embp[(size_t)33 * C7]; // emb@W_feed + b
__device__ __attribute__((aligned(16))) float g_hbuf[2][B * H];      // h_d double buffer
__device__ __attribute__((aligned(16))) float g_cd[B * H];           // c_d state
__device__ __attribute__((aligned(16))) float g_cb[B * H];           // c_bar state

// ---------------- fast transcendentals ----------------
__device__ __forceinline__ float sig_f(float x){
  return __builtin_amdgcn_rcpf(1.f + __builtin_amdgcn_exp2f(-1.44269504089f * x));
}
__device__ __forceinline__ float tanh_f(float x){
  float t = __builtin_amdgcn_exp2f(2.88539008178f * x);   // e^(2x)
  return 1.f - 2.f * __builtin_amdgcn_rcpf(t + 1.f);      // safe at +/-inf
}
__device__ __forceinline__ float softplus_f(float x){
  float p = __builtin_amdgcn_exp2f(-1.44269504089f * fabsf(x));
  // ln(1+p) = ln2 * log2(1+p)
  return fmaxf(x, 0.f) + 0.69314718056f * __builtin_amdgcn_logf(1.f + p);
}

// ---------------- DPP 16-lane-row sum (VALU pipe only) ----------------
template<int C>
__device__ __forceinline__ float dppadd(float a){
  int t = __builtin_amdgcn_mov_dpp(__float_as_int(a), C, 0xF, 0xF, true);
  return a + __int_as_float(t);
}
__device__ __forceinline__ float row16_sum(float a){
  a = dppadd<0xB1>(a);   // quad_perm [1,0,3,2]  (xor 1)
  a = dppadd<0x4E>(a);   // quad_perm [2,3,0,1]  (xor 2)
  a = dppadd<0x141>(a);  // row_half_mirror      (8-sum)
  a = dppadd<0x140>(a);  // row_mirror           (16-sum, all lanes)
  return a;
}

__device__ __forceinline__ float d4(f32x4 a, f32x4 b, float s){
  s = __builtin_fmaf(a.x, b.x, s); s = __builtin_fmaf(a.y, b.y, s);
  s = __builtin_fmaf(a.z, b.z, s); s = __builtin_fmaf(a.w, b.w, s);
  return s;
}

__device__ __forceinline__ void loadrow(const float* src, int ln, f32x4 hv[4]){
  const f32x4* p = (const f32x4*)src;
  #pragma unroll
  for (int i = 0; i < 4; ++i) hv[i] = p[i * 64 + ln];   // 16B/lane, coalesced
}

// weight slice: w[g][i] = Wt[(g*H+colb)*K2 + kofs + (i*64+ln)*4 .. +3]
__device__ __forceinline__ void load_wslice(const float* Wbase, int colb, int ln,
                                            int kofs, f32x4 w[NG][4]){
  #pragma unroll
  for (int g = 0; g < NG; ++g){
    const float* cp = Wbase + (size_t)(g * H + colb) * K2 + kofs;
    #pragma unroll
    for (int i = 0; i < 4; ++i) w[g][i] = *(const f32x4*)(cp + (i * 64 + ln) * 4);
  }
}

// compute one b-row's 7 gate partials and store 4 sixteen-lane partials each
__device__ __forceinline__ void row_partial(const f32x4 hv[4], const f32x4 w[NG][4],
                                            float* gp, int bi, int wv, int ln){
  float a[NG];
  #pragma unroll
  for (int g = 0; g < NG; ++g){
    float s = 0.f;
    #pragma unroll
    for (int i = 0; i < 4; ++i) s = d4(hv[i], w[g][i], s);
    a[g] = row16_sum(s);
  }
  int m = ln & 15;
  float v = a[0];
  v = (m==1)?a[1]:v; v = (m==2)?a[2]:v; v = (m==3)?a[3]:v;
  v = (m==4)?a[4]:v; v = (m==5)?a[5]:v; v = (m==6)?a[6]:v;
  if (m < NG) gp[bi * 112 + wv * 28 + m * 4 + (ln >> 4)] = v;
}

// NR rows from global src, software-pipelined one row ahead
template<int NR>
__device__ __forceinline__ void mm_block(const float* src, const f32x4 w[NG][4],
                                         float* gp, int wv, int ln){
  f32x4 ha[4], hb[4];
  loadrow(src, ln, ha);
  #pragma unroll
  for (int b = 0; b < NR; b += 2){
    if (b + 1 < NR) loadrow(src + (b + 1) * H, ln, hb);
    row_partial(ha, w, gp, b, wv, ln);
    if (b + 2 < NR) loadrow(src + (b + 2) * H, ln, ha);
    if (b + 1 < NR) row_partial(hb, w, gp, b + 1, wv, ln);
  }
}

// ---------------- kernels ----------------

// generic 64x64-tiled transpose: in[R][C] -> out[C][R]; out picked by selector
extern "C" __global__ void __launch_bounds__(256)
transpose_k(const float* __restrict__ in, int which, int R, int C){
  __shared__ float tls[64 * 65];
  float* out = (which == 0) ? g_Wt : (which == 1 ? g_w1t : g_w2t);
  int tx = threadIdx.x & 63, ty = threadIdx.x >> 6;
  size_t c0 = (size_t)blockIdx.x * 64, r0 = (size_t)blockIdx.y * 64;
  #pragma unroll
  for (int i = 0; i < 16; ++i){
    int r = i * 4 + ty;
    tls[r * 65 + tx] = in[(r0 + r) * (size_t)C + c0 + tx];
  }
  __syncthreads();
  #pragma unroll
  for (int i = 0; i < 16; ++i){
    int c = i * 4 + ty;
    out[(c0 + c) * (size_t)R + r0 + tx] = tls[tx * 65 + c];
  }
}

// emb_proj[e][col] = emb[e] @ rec_W[0:H][col] + rec_b[col]   (33 x 7168)
extern "C" __global__ void __launch_bounds__(256, 1)
embproj_k(const float* __restrict__ emb, const float* __restrict__ recb){
  __shared__ float gp[33 * 112];
  int tid = threadIdx.x, wg = blockIdx.x, wv = tid >> 6, ln = tid & 63;
  int colb = wg * 4 + wv;
  f32x4 w[NG][4];
  load_wslice(g_Wt, colb, ln, 0, w);          // feed half (k = 0..1023)
  mm_block<33>(emb, w, gp, wv, ln);
  __syncthreads();
  for (int idx = tid; idx < 33 * 4; idx += 256){
    int e = idx >> 2, hl = idx & 3, col = wg * 4 + hl;
    #pragma unroll
    for (int g = 0; g < NG; ++g){
      const float* pp = gp + e * 112 + hl * 28 + g * 4;
      g_embp[(size_t)e * C7 + g * H + col] =
          recb[g * H + col] + ((pp[0] + pp[1]) + (pp[2] + pp[3]));
    }
  }
}

// carry0 from emb_proj[0] (h=0, c=0), then decay with dur_0 -> h_d_0, state
extern "C" __global__ void __launch_bounds__(256)
init_k(const float* __restrict__ tm){
  int tid = threadIdx.x, wg = blockIdx.x;
  if (tid < 128){
    int b = tid >> 2, hl = tid & 3, col = wg * 4 + hl, si = b * H + col;
    float G[NG];
    #pragma unroll
    for (int g = 0; g < NG; ++g) G[g] = g_embp[(size_t)g * H + col]; // e = 0
    float gz = tanh_f(G[2]);
    float c  = sig_f(G[0]) * gz;          // c_tm1 = 0
    float cb = sig_f(G[4]) * gz;          // c_bar_tm1 = 0
    float dd = softplus_f(G[6]);
    float dur = tm[b * T];                // dur_0
    float cd = cb + (c - cb) * __builtin_amdgcn_exp2f(-1.44269504089f * dd * dur);
    g_cd[si] = cd; g_cb[si] = cb;
    g_hbuf[0][si] = sig_f(G[3]) * tanh_f(cd);   // h_d_0
  }
}

// step t (t=1..511): S_t = recurrence(e_{t-1}, h_d_{t-1}); decay dur_t -> h_d_t
extern "C" __global__ void __launch_bounds__(256, 1)
step_k(int t, const int* __restrict__ ev, const float* __restrict__ tm){
  __shared__ float gp[B * 112];
  int tid = threadIdx.x, wg = blockIdx.x, wv = tid >> 6, ln = tid & 63;
  int colb = wg * 4 + wv;
  f32x4 w[NG][4];
  load_wslice(g_Wt, colb, ln, H, w);          // recurrent half (k = 1024..2047)
  const float* hprev = g_hbuf[(t - 1) & 1];
  mm_block<B>(hprev, w, gp, wv, ln);
  __syncthreads();
  if (tid < 128){
    int b = tid >> 2, hl = tid & 3, col = wg * 4 + hl, si = b * H + col;
    int e = ev[b * T + t - 1];
    const float* ep = g_embp + (size_t)e * C7 + col;
    float G[NG];
    #pragma unroll
    for (int g = 0; g < NG; ++g){
      const float* pp = gp + b * 112 + hl * 28 + g * 4;
      G[g] = ep[(size_t)g * H] + ((pp[0] + pp[1]) + (pp[2] + pp[3]));
    }
    float gz  = tanh_f(G[2]);
    float cdp = g_cd[si], cbp = g_cb[si];
    float c   = sig_f(G[1]) * cdp + sig_f(G[0]) * gz;
    float cb  = sig_f(G[5]) * cbp + sig_f(G[4]) * gz;
    float dd  = softplus_f(G[6]);
    float dur = tm[b * T + t];
    float cd  = cb + (c - cb) * __builtin_amdgcn_exp2f(-1.44269504089f * dd * dur);
    g_cd[si] = cd; g_cb[si] = cb;
    g_hbuf[t & 1][si] = sig_f(G[3]) * tanh_f(cd);
  }
}

// phase 0: hid = relu(h_last @ w1 + b1) -> g_hbuf[0]
// phase 1: out = hid @ w2 + b2         -> outp
extern "C" __global__ void __launch_bounds__(256, 1)
mlp_k(int phase, const float* __restrict__ bias, float* __restrict__ outp){
  __shared__ float gp[B * 16];
  int tid = threadIdx.x, wg = blockIdx.x, wv = tid >> 6, ln = tid & 63;
  int colb = wg * 4 + wv;
  const float* Wt   = phase ? g_w2t : g_w1t;
  const float* hsrc = phase ? g_hbuf[0] : g_hbuf[1];   // h_last = buf[511&1]=1
  f32x4 w[4];
  #pragma unroll
  for (int i = 0; i < 4; ++i)
    w[i] = *(const f32x4*)(Wt + (size_t)colb * H + (i * 64 + ln) * 4);
  #pragma unroll 2
  for (int b = 0; b < B; ++b){
    f32x4 hv[4]; loadrow(hsrc + b * H, ln, hv);
    float s = 0.f;
    #pragma unroll
    for (int i = 0; i < 4; ++i) s = d4(hv[i], w[i], s);
    s = row16_sum(s);
    if ((ln & 15) == 0) gp[b * 16 + wv * 4 + (ln >> 4)] = s;
  }
  __syncthreads();
  if (tid < 128){
    int b = tid >> 2, hl = tid & 3, col = wg * 4 + hl;
    const float* pp = gp + b * 16 + hl * 4;
    float s = ((pp[0] + pp[1]) + (pp[2] + pp[3])) + bias[col];
    if (!phase) g_hbuf[0][b * H + col] = fmaxf(s, 0.f);
    else        outp[b * H + col] = s;
  }
}

// ---------------- host ----------------
extern "C" void kernel_launch(void* const* d_in, const int* in_sizes, int n_in,
                              void* d_out, int out_size, void* d_ws, size_t ws_size,
                              hipStream_t stream)
{
  const int*   ev = (const int*)  d_in[0];
  const float* tm = (const float*)d_in[1];
  const float* rW = (const float*)d_in[2];
  const float* rb = (const float*)d_in[3];
  const float* em = (const float*)d_in[4];
  const float* w1 = (const float*)d_in[5];
  const float* b1 = (const float*)d_in[6];
  const float* w2 = (const float*)d_in[7];
  const float* b2 = (const float*)d_in[8];
  float* outp = (float*)d_out;
  (void)d_ws; (void)ws_size; (void)in_sizes; (void)n_in; (void)out_size;

  dim3 blk(256);
  // prologue: transposes + emb projection + initial carry
  hipLaunchKernelGGL(transpose_k, dim3(C7 / 64, K2 / 64), blk, 0, stream, rW, 0, K2, C7);
  hipLaunchKernelGGL(transpose_k, dim3(H / 64, H / 64),  blk, 0, stream, w1, 1, H, H);
  hipLaunchKernelGGL(transpose_k, dim3(H / 64, H / 64),  blk, 0, stream, w2, 2, H, H);
  hipLaunchKernelGGL(embproj_k, dim3(NWG), blk, 0, stream, em, rb);
  hipLaunchKernelGGL(init_k,    dim3(NWG), blk, 0, stream, tm);
  // sequential scan: one launch per step (launch boundary = device-wide sync)
  for (int t = 1; t < T; ++t)
    hipLaunchKernelGGL(step_k, dim3(NWG), blk, 0, stream, t, ev, tm);
  // MLP head
  hipLaunchKernelGGL(mlp_k, dim3(NWG), blk, 0, stream, 0, b1, outp);
  hipLaunchKernelGGL(mlp_k, dim3(NWG), blk, 0, stream, 1, b2, outp);
}